// Round 1
// baseline (868.332 us; speedup 1.0000x reference)
//
#include <hip/hip_runtime.h>

// Fused Conv1d(k=3,pad=1) + BN(inference) + 4-step LIF + residual.
// x: (L=2048, TB=128, D=128) f32. conv_w: (D,D,3). out: (L,TB,D) f32.
// out[l,n,d] = x[l,n,d] + spike[n,d,l], LIF scan over t where n = t*32+b.

constexpr int L   = 2048;
constexpr int NTB = 128;
constexpr int D   = 128;
constexpr int T   = 4;
constexpr int LT  = 64;        // l-tile per block
constexpr int NP  = LT + 2;    // 66 staged positions (halo)
constexpr int IT  = 16;        // i-tile (input channels per LDS weight stage)
constexpr int WROW = IT * 3 + 4;  // 52 floats per o-row (pad kills b128 conflicts)

__global__ __launch_bounds__(256, 2)
void snn_conv_lif(const float* __restrict__ x, const float* __restrict__ w,
                  const float* __restrict__ gamma, const float* __restrict__ beta,
                  const float* __restrict__ mean, const float* __restrict__ var,
                  float* __restrict__ out) {
    __shared__ float xs[NP * D];       // [pos][i], 33792 B
    __shared__ float ws[D * WROW];     // [o][i_loc*3+k], 26624 B

    const int tid = threadIdx.x;
    const int b   = blockIdx.x & 31;
    const int lt  = blockIdx.x >> 5;
    const int l0  = lt * LT;
    const int o   = tid & 127;         // output channel
    const int lh  = tid >> 7;          // which 32-wide l half
    const int p0  = lh * 32;

    // BN folded: y = conv*sc + bi
    const float sc = gamma[o] / sqrtf(var[o] + 1e-5f);
    const float bi = beta[o] - mean[o] * sc;

    float v[32];
    #pragma unroll
    for (int j = 0; j < 32; ++j) v[j] = 0.f;

    for (int t = 0; t < T; ++t) {
        const int n = t * 32 + b;
        __syncthreads();   // protect xs from previous epilogue readers
        // ---- stage x[l0-1 .. l0+64][n][:] into xs[pos][i] ----
        for (int idx = tid; idx < NP * 32; idx += 256) {
            const int p = idx >> 5, c = idx & 31;
            const int l = l0 - 1 + p;
            float4 val = make_float4(0.f, 0.f, 0.f, 0.f);
            if (l >= 0 && l < L)
                val = ((const float4*)x)[l * (NTB * D / 4) + n * (D / 4) + c];
            ((float4*)xs)[p * (D / 4) + c] = val;
        }

        float acc[32];
        #pragma unroll
        for (int j = 0; j < 32; ++j) acc[j] = 0.f;

        for (int it = 0; it < D / IT; ++it) {
            __syncthreads();  // ws reuse guard (also covers xs ready at it==0)
            // ---- stage weight i-tile: ws[o][i_loc*3+k] ----
            for (int idx = tid; idx < D * 12; idx += 256) {
                const int oo = idx / 12, c = idx % 12;
                float4 wv = ((const float4*)(w + oo * (D * 3) + it * (IT * 3)))[c];
                *((float4*)(ws + oo * WROW + c * 4)) = wv;
            }
            __syncthreads();

            const float* wrow = ws + o * WROW;
            #pragma unroll
            for (int i4 = 0; i4 < IT / 4; ++i4) {
                const float4 w0 = *((const float4*)(wrow + i4 * 12));
                const float4 w1 = *((const float4*)(wrow + i4 * 12 + 4));
                const float4 w2 = *((const float4*)(wrow + i4 * 12 + 8));
                // wr[i_loc*3 + k] for 4 i's
                const float wr[12] = {w0.x, w0.y, w0.z, w0.w,
                                      w1.x, w1.y, w1.z, w1.w,
                                      w2.x, w2.y, w2.z, w2.w};
                const float4* xcol = (const float4*)xs + (it * 4 + i4);
                float4 xa = xcol[(p0 + 0) * (D / 4)];
                float4 xb = xcol[(p0 + 1) * (D / 4)];
                #pragma unroll
                for (int j = 0; j < 32; ++j) {
                    const float4 xc = xcol[(p0 + j + 2) * (D / 4)];
                    float s = acc[j];
                    s = fmaf(xa.x, wr[0], s);  // k=0, i+0
                    s = fmaf(xa.y, wr[3], s);  // k=0, i+1
                    s = fmaf(xa.z, wr[6], s);
                    s = fmaf(xa.w, wr[9], s);
                    s = fmaf(xb.x, wr[1], s);  // k=1
                    s = fmaf(xb.y, wr[4], s);
                    s = fmaf(xb.z, wr[7], s);
                    s = fmaf(xb.w, wr[10], s);
                    s = fmaf(xc.x, wr[2], s);  // k=2
                    s = fmaf(xc.y, wr[5], s);
                    s = fmaf(xc.z, wr[8], s);
                    s = fmaf(xc.w, wr[11], s);
                    acc[j] = s;
                    xa = xb; xb = xc;
                }
            }
        }

        // ---- BN + LIF step + residual + store ----
        #pragma unroll
        for (int j = 0; j < 32; ++j) {
            const float y = fmaf(acc[j], sc, bi);
            const float h = 0.5f * (v[j] + y);       // v + (y - v)/tau, tau=2
            const bool fire = (h >= 1.0f);
            v[j] = fire ? 0.0f : h;                  // hard reset
            const float s = fire ? 1.0f : 0.0f;
            const int l = l0 + p0 + j;
            out[l * (NTB * D) + n * D + o] = xs[(p0 + j + 1) * D + o] + s;
        }
    }
}

extern "C" void kernel_launch(void* const* d_in, const int* in_sizes, int n_in,
                              void* d_out, int out_size, void* d_ws, size_t ws_size,
                              hipStream_t stream) {
    const float* x     = (const float*)d_in[0];
    const float* w     = (const float*)d_in[1];
    const float* gamma = (const float*)d_in[2];
    const float* beta  = (const float*)d_in[3];
    const float* mean  = (const float*)d_in[4];
    const float* var   = (const float*)d_in[5];
    float* out = (float*)d_out;

    dim3 grid((L / LT) * 32);   // 32 l-tiles × 32 b values = 1024 blocks
    dim3 block(256);
    snn_conv_lif<<<grid, block, 0, stream>>>(x, w, gamma, beta, mean, var, out);
}

// Round 2
// 686.672 us; speedup vs baseline: 1.2646x; 1.2646x over previous
//
#include <hip/hip_runtime.h>

// Fused Conv1d(k=3,pad=1) + BN(inference) + 4-step LIF + residual.
// x: (L=2048, TB=128, D=128) f32. conv_w: (D,D,3). out: (L,TB,D) f32.
// out[l,n,d] = x[l,n,d] + spike[n,d,l], LIF scan over t where n = t*32+b.
//
// R2: occupancy push. LT 64->32, IT 16->8 => LDS 59KB -> 31KB/block,
// acc/v arrays 32->16 => ~4-5 blocks/CU (was 2). Same accumulation order.

constexpr int L   = 2048;
constexpr int NTB = 128;
constexpr int D   = 128;
constexpr int T   = 4;
constexpr int LT  = 32;        // l-tile per block
constexpr int NP  = LT + 2;    // 34 staged positions (halo)
constexpr int JT  = LT / 2;    // 16 l-positions per thread
constexpr int IT  = 8;         // i-tile (input channels per LDS weight stage)
constexpr int WROW = IT * 3 + 4;  // 28 floats per o-row (pad breaks pow2 stride)

__global__ __launch_bounds__(256, 4)
void snn_conv_lif(const float* __restrict__ x, const float* __restrict__ w,
                  const float* __restrict__ gamma, const float* __restrict__ beta,
                  const float* __restrict__ mean, const float* __restrict__ var,
                  float* __restrict__ out) {
    __shared__ float xs[NP * D];       // [pos][i], 17408 B
    __shared__ float ws[D * WROW];     // [o][i_loc*3+k], 14336 B  (total 31744 B)

    const int tid = threadIdx.x;
    const int b   = blockIdx.x & 31;
    const int lt  = blockIdx.x >> 5;
    const int l0  = lt * LT;
    const int o   = tid & 127;         // output channel
    const int lh  = tid >> 7;          // which 16-wide l half
    const int p0  = lh * JT;

    // BN folded: y = conv*sc + bi
    const float sc = gamma[o] / sqrtf(var[o] + 1e-5f);
    const float bi = beta[o] - mean[o] * sc;

    float v[JT];
    #pragma unroll
    for (int j = 0; j < JT; ++j) v[j] = 0.f;

    for (int t = 0; t < T; ++t) {
        const int n = t * 32 + b;
        __syncthreads();   // protect xs from previous epilogue readers
        // ---- stage x[l0-1 .. l0+LT][n][:] into xs[pos][i] ----
        for (int idx = tid; idx < NP * 32; idx += 256) {
            const int p = idx >> 5, c = idx & 31;
            const int l = l0 - 1 + p;
            float4 val = make_float4(0.f, 0.f, 0.f, 0.f);
            if (l >= 0 && l < L)
                val = ((const float4*)x)[l * (NTB * D / 4) + n * (D / 4) + c];
            ((float4*)xs)[p * (D / 4) + c] = val;
        }

        float acc[JT];
        #pragma unroll
        for (int j = 0; j < JT; ++j) acc[j] = 0.f;

        for (int it = 0; it < D / IT; ++it) {
            __syncthreads();  // ws reuse guard (also covers xs ready at it==0)
            // ---- stage weight i-tile: ws[o][i_loc*3+k] (6 float4 per o-row) ----
            for (int idx = tid; idx < D * 6; idx += 256) {
                const int oo = idx / 6, c = idx % 6;
                float4 wv = ((const float4*)(w + oo * (D * 3) + it * (IT * 3)))[c];
                *((float4*)(ws + oo * WROW + c * 4)) = wv;
            }
            __syncthreads();

            const float* wrow = ws + o * WROW;
            #pragma unroll
            for (int i4 = 0; i4 < IT / 4; ++i4) {
                const float4 w0 = *((const float4*)(wrow + i4 * 12));
                const float4 w1 = *((const float4*)(wrow + i4 * 12 + 4));
                const float4 w2 = *((const float4*)(wrow + i4 * 12 + 8));
                // wr[i_loc*3 + k] for 4 i's
                const float wr[12] = {w0.x, w0.y, w0.z, w0.w,
                                      w1.x, w1.y, w1.z, w1.w,
                                      w2.x, w2.y, w2.z, w2.w};
                const float4* xcol = (const float4*)xs + (it * 2 + i4);
                float4 xa = xcol[(p0 + 0) * (D / 4)];
                float4 xb = xcol[(p0 + 1) * (D / 4)];
                #pragma unroll
                for (int j = 0; j < JT; ++j) {
                    const float4 xc = xcol[(p0 + j + 2) * (D / 4)];
                    float s = acc[j];
                    s = fmaf(xa.x, wr[0], s);  // k=0, i+0
                    s = fmaf(xa.y, wr[3], s);  // k=0, i+1
                    s = fmaf(xa.z, wr[6], s);
                    s = fmaf(xa.w, wr[9], s);
                    s = fmaf(xb.x, wr[1], s);  // k=1
                    s = fmaf(xb.y, wr[4], s);
                    s = fmaf(xb.z, wr[7], s);
                    s = fmaf(xb.w, wr[10], s);
                    s = fmaf(xc.x, wr[2], s);  // k=2
                    s = fmaf(xc.y, wr[5], s);
                    s = fmaf(xc.z, wr[8], s);
                    s = fmaf(xc.w, wr[11], s);
                    acc[j] = s;
                    xa = xb; xb = xc;
                }
            }
        }

        // ---- BN + LIF step + residual + store ----
        #pragma unroll
        for (int j = 0; j < JT; ++j) {
            const float y = fmaf(acc[j], sc, bi);
            const float h = 0.5f * (v[j] + y);       // v + (y - v)/tau, tau=2
            const bool fire = (h >= 1.0f);
            v[j] = fire ? 0.0f : h;                  // hard reset
            const float s = fire ? 1.0f : 0.0f;
            const int l = l0 + p0 + j;
            out[l * (NTB * D) + n * D + o] = xs[(p0 + j + 1) * D + o] + s;
        }
    }
}

extern "C" void kernel_launch(void* const* d_in, const int* in_sizes, int n_in,
                              void* d_out, int out_size, void* d_ws, size_t ws_size,
                              hipStream_t stream) {
    const float* x     = (const float*)d_in[0];
    const float* w     = (const float*)d_in[1];
    const float* gamma = (const float*)d_in[2];
    const float* beta  = (const float*)d_in[3];
    const float* mean  = (const float*)d_in[4];
    const float* var   = (const float*)d_in[5];
    float* out = (float*)d_out;

    dim3 grid((L / LT) * 32);   // 64 l-tiles x 32 b values = 2048 blocks
    dim3 block(256);
    snn_conv_lif<<<grid, block, 0, stream>>>(x, w, gamma, beta, mean, var, out);
}